// Round 1
// baseline (1353.103 us; speedup 1.0000x reference)
//
#include <hip/hip_runtime.h>
#include <math.h>

#define T_TOKENS 16384
#define H_DIM 1024
#define F_DIM 2048
#define E_NUM 8
#define MAX_TILES 264                  // 32768/128 + 8 (worst-case per-expert padding)
#define MAX_PAIRS (MAX_TILES * 128)    // 33792

typedef __attribute__((ext_vector_type(8))) short bf16x8;
typedef __attribute__((ext_vector_type(4))) float f32x4;
typedef __attribute__((ext_vector_type(4))) unsigned short us4;

struct TopK { int e0, e1; float w0, w1; };

__device__ __forceinline__ unsigned short f2bf(float f) {
  unsigned int u = __float_as_uint(f);
  u = (u + 0x7fffu + ((u >> 16) & 1u)) >> 16;
  return (unsigned short)u;
}

__device__ __forceinline__ void gload_lds16(const void* g, void* l) {
  __builtin_amdgcn_global_load_lds(
      (const __attribute__((address_space(1))) void*)g,
      (__attribute__((address_space(3))) void*)l, 16, 0, 0);
}

// ---------------- cast + transpose weights: in [E][R][C] f32 -> out [E][C][R] bf16
__global__ __launch_bounds__(256) void transpose_cast(
    const float* __restrict__ in, unsigned short* __restrict__ out, int R, int C) {
  __shared__ float tile[64][65];
  int e = blockIdx.z;
  int r0 = blockIdx.y * 64, c0 = blockIdx.x * 64;
  int c = threadIdx.x & 63, r4 = threadIdx.x >> 6;
  const float* src = in + ((size_t)e * R + r0) * C + c0;
#pragma unroll
  for (int i = 0; i < 16; i++) {
    int r = r4 + i * 4;
    tile[r][c] = src[(size_t)r * C + c];
  }
  __syncthreads();
  unsigned short* dst = out + ((size_t)e * C + c0) * R + r0;
#pragma unroll
  for (int i = 0; i < 16; i++) {
    int r = r4 + i * 4;
    dst[(size_t)r * R + c] = f2bf(tile[c][r]);
  }
}

// ---------------- router: logits, softmax, top-2, losses, counts, x->bf16
__global__ __launch_bounds__(256) void router_kernel(
    const float* __restrict__ x, const float* __restrict__ Wg,
    unsigned short* __restrict__ xb, TopK* __restrict__ topk,
    int* __restrict__ counts, float* __restrict__ scal) {
  __shared__ float wg[E_NUM][H_DIM];
  int tid = threadIdx.x;
  for (int i = tid; i < E_NUM * H_DIM; i += 256) {
    int h = i >> 3, e = i & 7;
    wg[e][h] = Wg[i];
  }
  __syncthreads();
  int lane = tid & 63, wid = tid >> 6;
  float zacc = 0.f, c0 = 0.f, c1 = 0.f, s0 = 0.f, s1 = 0.f;
  for (int t = blockIdx.x * 4 + wid; t < T_TOKENS; t += gridDim.x * 4) {
    float l[E_NUM];
#pragma unroll
    for (int e = 0; e < E_NUM; e++) l[e] = 0.f;
    const float* xrow = x + (size_t)t * H_DIM;
    unsigned short* xbrow = xb + (size_t)t * H_DIM;
#pragma unroll
    for (int i = 0; i < H_DIM / 64; i++) {
      int h = lane + i * 64;
      float xv = xrow[h];
      xbrow[h] = f2bf(xv);
#pragma unroll
      for (int e = 0; e < E_NUM; e++) l[e] = fmaf(xv, wg[e][h], l[e]);
    }
#pragma unroll
    for (int off = 32; off > 0; off >>= 1) {
#pragma unroll
      for (int e = 0; e < E_NUM; e++) l[e] += __shfl_xor(l[e], off, 64);
    }
    float mx = l[0];
#pragma unroll
    for (int e = 1; e < E_NUM; e++) mx = fmaxf(mx, l[e]);
    float p[E_NUM]; float se = 0.f;
#pragma unroll
    for (int e = 0; e < E_NUM; e++) { p[e] = expf(l[e] - mx); se += p[e]; }
    float logz = logf(se) + mx;
    int e0 = 0; float b0 = p[0];
#pragma unroll
    for (int e = 1; e < E_NUM; e++) if (p[e] > b0) { b0 = p[e]; e0 = e; }
    int e1 = -1; float b1 = -1.f;
#pragma unroll
    for (int e = 0; e < E_NUM; e++) if (e != e0 && p[e] > b1) { b1 = p[e]; e1 = e; }
    float w0 = b0 / se, w1 = b1 / se;
    if (lane == 0) {
      TopK tk; tk.e0 = e0; tk.e1 = e1; tk.w0 = w0; tk.w1 = w1;
      topk[t] = tk;
      atomicAdd(&counts[e0], 1);
      atomicAdd(&counts[e1], 1);
      zacc += logz * logz;
      c0 += (e0 == 0 || e1 == 0) ? 1.f : 0.f;
      c1 += (e0 == 1 || e1 == 1) ? 1.f : 0.f;
      s0 += w0; s1 += w1;
    }
  }
  if (lane == 0) {
    atomicAdd(&scal[0], zacc);
    atomicAdd(&scal[1], c0);
    atomicAdd(&scal[2], c1);
    atomicAdd(&scal[3], s0);
    atomicAdd(&scal[4], s1);
  }
}

// ---------------- offsets padded to 128 rows, tile->expert map
__global__ void scan_kernel(const int* __restrict__ counts, int* __restrict__ po,
                            int* __restrict__ tile_expert) {
  if (threadIdx.x == 0) {
    int off = 0, ti = 0;
    for (int e = 0; e < E_NUM; e++) {
      po[e] = off;
      int nt = (counts[e] + 127) >> 7;
      for (int j = 0; j < nt; j++) tile_expert[ti++] = e;
      off += nt << 7;
    }
    while (ti < MAX_TILES) tile_expert[ti++] = -1;
  }
}

__global__ __launch_bounds__(256) void assign_kernel(
    const TopK* __restrict__ topk, const int* __restrict__ po,
    int* __restrict__ cursors, int* __restrict__ pair_token,
    float* __restrict__ pair_w) {
  int t = blockIdx.x * 256 + threadIdx.x;
  if (t >= T_TOKENS) return;
  TopK tk = topk[t];
  int p0 = po[tk.e0] + atomicAdd(&cursors[tk.e0], 1);
  pair_token[p0] = t; pair_w[p0] = tk.w0;
  int p1 = po[tk.e1] + atomicAdd(&cursors[tk.e1], 1);
  pair_token[p1] = t; pair_w[p1] = tk.w1;
}

// ---------------- grouped GEMM, 128x128 tile, 16x16x32 bf16 MFMA
// MODE 0: Hmid[p,:] = gelu(xb[tok(p),:] @ W1t[e]^T)   (K=1024, N=2048)
// MODE 1: out[tok(p),:] += w(p) * (Hmid[p,:] @ W2t[e]^T)  (K=2048, N=1024)
template <int MODE, int K, int N>
__global__ __launch_bounds__(256, 2) void moe_gemm(
    const unsigned short* __restrict__ A, const unsigned short* __restrict__ Bt,
    const int* __restrict__ pair_token, const float* __restrict__ pair_w,
    const int* __restrict__ tile_expert,
    unsigned short* __restrict__ hmid, float* __restrict__ outp) {
  int mt = blockIdx.y;
  int e = tile_expert[mt];
  if (e < 0) return;
  int m0 = mt << 7;
  int n0 = blockIdx.x << 7;
  __shared__ __align__(16) unsigned short As[128 * 32];
  __shared__ __align__(16) unsigned short Bs[128 * 32];
  int tid = threadIdx.x, lane = tid & 63, wid = tid >> 6;
  int wm = wid >> 1, wn = wid & 1;
  int lo = lane & 15, hi = lane >> 4;
  int hi8 = hi * 8;

  // staging: thread tid owns 16B chunks tid and tid+256 of each 8KB tile
  int rA = tid >> 2;              // row 0..63 (set1), +64 (set2)
  int kof = (tid & 3) * 8;        // k element offset within 32
  size_t aOff1, aOff2;
  if (MODE == 0) {
    int t1 = pair_token[m0 + rA];      if (t1 < 0) t1 = 0;
    int t2 = pair_token[m0 + rA + 64]; if (t2 < 0) t2 = 0;
    aOff1 = (size_t)t1 * K + kof;
    aOff2 = (size_t)t2 * K + kof;
  } else {
    aOff1 = (size_t)(m0 + rA) * K + kof;
    aOff2 = (size_t)(m0 + rA + 64) * K + kof;
  }
  const unsigned short* aP1 = A + aOff1;
  const unsigned short* aP2 = A + aOff2;
  const unsigned short* bP1 = Bt + ((size_t)e * N + n0 + rA) * K + kof;
  const unsigned short* bP2 = bP1 + (size_t)64 * K;

  unsigned short* AsD1 = As + wid * 512;
  unsigned short* AsD2 = As + 2048 + wid * 512;
  unsigned short* BsD1 = Bs + wid * 512;
  unsigned short* BsD2 = Bs + 2048 + wid * 512;

  f32x4 acc[4][4];
#pragma unroll
  for (int i = 0; i < 4; i++)
#pragma unroll
    for (int j = 0; j < 4; j++) acc[i][j] = (f32x4){0.f, 0.f, 0.f, 0.f};

  for (int k0 = 0; k0 < K; k0 += 32) {
    gload_lds16(aP1, AsD1);
    gload_lds16(aP2, AsD2);
    gload_lds16(bP1, BsD1);
    gload_lds16(bP2, BsD2);
    aP1 += 32; aP2 += 32; bP1 += 32; bP2 += 32;
    __syncthreads();
    bf16x8 af[4], bfv[4];
#pragma unroll
    for (int mf = 0; mf < 4; mf++)
      af[mf] = *(const bf16x8*)&As[(wm * 64 + mf * 16 + lo) * 32 + hi8];
#pragma unroll
    for (int nf = 0; nf < 4; nf++)
      bfv[nf] = *(const bf16x8*)&Bs[(wn * 64 + nf * 16 + lo) * 32 + hi8];
#pragma unroll
    for (int mf = 0; mf < 4; mf++)
#pragma unroll
      for (int nf = 0; nf < 4; nf++)
        // swapped operands: D[n-col = 4*hi+r][token = lo]
        acc[mf][nf] = __builtin_amdgcn_mfma_f32_16x16x32_bf16(
            bfv[nf], af[mf], acc[mf][nf], 0, 0, 0);
    __syncthreads();
  }

  if (MODE == 0) {
#pragma unroll
    for (int mf = 0; mf < 4; mf++) {
      size_t p = m0 + wm * 64 + mf * 16 + lo;
#pragma unroll
      for (int nf = 0; nf < 4; nf++) {
        int f = n0 + wn * 64 + nf * 16 + hi * 4;
        us4 pk;
#pragma unroll
        for (int r = 0; r < 4; r++) {
          float v = acc[mf][nf][r];
          v = 0.5f * v * (1.f + erff(v * 0.70710678118654752f));  // exact gelu
          pk[r] = f2bf(v);
        }
        *(us4*)&hmid[p * (size_t)N + f] = pk;
      }
    }
  } else {
#pragma unroll
    for (int mf = 0; mf < 4; mf++) {
      int p = m0 + wm * 64 + mf * 16 + lo;
      int t = pair_token[p];
      if (t < 0) continue;
      float w = pair_w[p];
      float* orow = outp + (size_t)t * N;
#pragma unroll
      for (int nf = 0; nf < 4; nf++) {
        int h = n0 + wn * 64 + nf * 16 + hi * 4;
#pragma unroll
        for (int r = 0; r < 4; r++)
          atomicAdd(&orow[h + r], w * acc[mf][nf][r]);
      }
    }
  }
}

__global__ void finalize_kernel(const float* __restrict__ scal,
                                float* __restrict__ outTail) {
  if (threadIdx.x == 0 && blockIdx.x == 0) {
    float invT = 1.f / (float)T_TOKENS;
    outTail[0] = scal[0] * invT;  // z_loss
    float tpe0 = scal[1] * invT, tpe1 = scal[2] * invT;
    float rp0 = scal[3] * invT, rp1 = scal[4] * invT;
    outTail[1] = (tpe0 * rp0 + tpe1 * rp1) * 0.5f * 4.f;  // aux (K=2 one_hot path)
  }
}

extern "C" void kernel_launch(void* const* d_in, const int* in_sizes, int n_in,
                              void* d_out, int out_size, void* d_ws, size_t ws_size,
                              hipStream_t stream) {
  const float* x  = (const float*)d_in[0];
  const float* Wg = (const float*)d_in[1];
  const float* W1 = (const float*)d_in[2];
  const float* W2 = (const float*)d_in[3];
  float* outp = (float*)d_out;

  char* w = (char*)d_ws;
  auto alloc = [&](size_t b) { char* p = w; w += (b + 511) & ~(size_t)511; return p; };
  float* scal        = (float*)alloc(32);
  int*   counts      = (int*)alloc(32);
  int*   cursors     = (int*)alloc(32);
  int*   po          = (int*)alloc(32);
  int*   tile_expert = (int*)alloc(MAX_TILES * 4);
  TopK*  topk        = (TopK*)alloc((size_t)T_TOKENS * sizeof(TopK));
  int*   pair_token  = (int*)alloc((size_t)MAX_PAIRS * 4);
  float* pair_w      = (float*)alloc((size_t)MAX_PAIRS * 4);
  unsigned short* xb   = (unsigned short*)alloc((size_t)T_TOKENS * H_DIM * 2);
  unsigned short* w1t  = (unsigned short*)alloc((size_t)E_NUM * F_DIM * H_DIM * 2);
  unsigned short* w2t  = (unsigned short*)alloc((size_t)E_NUM * H_DIM * F_DIM * 2);
  unsigned short* hmid = (unsigned short*)alloc((size_t)MAX_PAIRS * F_DIM * 2);

  hipMemsetAsync(d_out, 0, (size_t)out_size * sizeof(float), stream);
  hipMemsetAsync(scal, 0, 32, stream);
  hipMemsetAsync(counts, 0, 32, stream);
  hipMemsetAsync(cursors, 0, 32, stream);
  hipMemsetAsync(pair_token, 0xFF, (size_t)MAX_PAIRS * 4, stream);  // -1

  dim3 b256(256);
  // W1 [E][H][F] -> w1t [E][F][H]; W2 [E][F][H] -> w2t [E][H][F]
  transpose_cast<<<dim3(F_DIM / 64, H_DIM / 64, E_NUM), b256, 0, stream>>>(W1, w1t, H_DIM, F_DIM);
  transpose_cast<<<dim3(H_DIM / 64, F_DIM / 64, E_NUM), b256, 0, stream>>>(W2, w2t, F_DIM, H_DIM);
  router_kernel<<<512, b256, 0, stream>>>(x, Wg, xb, topk, counts, scal);
  scan_kernel<<<1, 64, 0, stream>>>(counts, po, tile_expert);
  assign_kernel<<<T_TOKENS / 256, b256, 0, stream>>>(topk, po, cursors, pair_token, pair_w);
  moe_gemm<0, H_DIM, F_DIM><<<dim3(F_DIM / 128, MAX_TILES), b256, 0, stream>>>(
      xb, w1t, pair_token, pair_w, tile_expert, hmid, nullptr);
  moe_gemm<1, F_DIM, H_DIM><<<dim3(H_DIM / 128, MAX_TILES), b256, 0, stream>>>(
      hmid, w2t, pair_token, pair_w, tile_expert, nullptr, outp);
  finalize_kernel<<<1, 64, 0, stream>>>(scal, outp + (size_t)T_TOKENS * H_DIM);
}

// Round 2
// 1086.357 us; speedup vs baseline: 1.2455x; 1.2455x over previous
//
#include <hip/hip_runtime.h>
#include <math.h>

#define T_TOKENS 16384
#define H_DIM 1024
#define F_DIM 2048
#define E_NUM 8
#define TILES_PER_RANK 136             // 16384/128 + 8 pad tiles (per rank)
#define TOT_TILES (2 * TILES_PER_RANK) // 272
#define MAX_PAIRS (TOT_TILES * 128)    // 34816

typedef __attribute__((ext_vector_type(8))) short bf16x8;
typedef __attribute__((ext_vector_type(4))) float f32x4;
typedef __attribute__((ext_vector_type(4))) unsigned short us4;

struct TopK { int e0, e1; float w0, w1; };

__device__ __forceinline__ unsigned short f2bf(float f) {
  unsigned int u = __float_as_uint(f);
  u = (u + 0x7fffu + ((u >> 16) & 1u)) >> 16;
  return (unsigned short)u;
}

__device__ __forceinline__ void gload_lds16(const void* g, void* l) {
  __builtin_amdgcn_global_load_lds(
      (const __attribute__((address_space(1))) void*)g,
      (__attribute__((address_space(3))) void*)l, 16, 0, 0);
}

// ---------------- cast + transpose weights: in [E][R][C] f32 -> out [E][C][R] bf16
__global__ __launch_bounds__(256) void transpose_cast(
    const float* __restrict__ in, unsigned short* __restrict__ out, int R, int C) {
  __shared__ float tile[64][65];
  int e = blockIdx.z;
  int r0 = blockIdx.y * 64, c0 = blockIdx.x * 64;
  int c = threadIdx.x & 63, r4 = threadIdx.x >> 6;
  const float* src = in + ((size_t)e * R + r0) * C + c0;
#pragma unroll
  for (int i = 0; i < 16; i++) {
    int r = r4 + i * 4;
    tile[r][c] = src[(size_t)r * C + c];
  }
  __syncthreads();
  unsigned short* dst = out + ((size_t)e * C + c0) * R + r0;
#pragma unroll
  for (int i = 0; i < 16; i++) {
    int r = r4 + i * 4;
    dst[(size_t)r * R + c] = f2bf(tile[c][r]);
  }
}

// ---------------- router: logits, softmax, top-2, losses, counts (by rank), x->bf16
__global__ __launch_bounds__(256) void router_kernel(
    const float* __restrict__ x, const float* __restrict__ Wg,
    unsigned short* __restrict__ xb, TopK* __restrict__ topk,
    int* __restrict__ counts, float* __restrict__ scal) {
  __shared__ float wg[E_NUM][H_DIM];
  int tid = threadIdx.x;
  for (int i = tid; i < E_NUM * H_DIM; i += 256) {
    int h = i >> 3, e = i & 7;
    wg[e][h] = Wg[i];
  }
  __syncthreads();
  int lane = tid & 63, wid = tid >> 6;
  float zacc = 0.f, c0 = 0.f, c1 = 0.f, s0 = 0.f, s1 = 0.f;
  for (int t = blockIdx.x * 4 + wid; t < T_TOKENS; t += gridDim.x * 4) {
    float l[E_NUM];
#pragma unroll
    for (int e = 0; e < E_NUM; e++) l[e] = 0.f;
    const float* xrow = x + (size_t)t * H_DIM;
    unsigned short* xbrow = xb + (size_t)t * H_DIM;
#pragma unroll
    for (int i = 0; i < H_DIM / 64; i++) {
      int h = lane + i * 64;
      float xv = xrow[h];
      xbrow[h] = f2bf(xv);
#pragma unroll
      for (int e = 0; e < E_NUM; e++) l[e] = fmaf(xv, wg[e][h], l[e]);
    }
#pragma unroll
    for (int off = 32; off > 0; off >>= 1) {
#pragma unroll
      for (int e = 0; e < E_NUM; e++) l[e] += __shfl_xor(l[e], off, 64);
    }
    float mx = l[0];
#pragma unroll
    for (int e = 1; e < E_NUM; e++) mx = fmaxf(mx, l[e]);
    float p[E_NUM]; float se = 0.f;
#pragma unroll
    for (int e = 0; e < E_NUM; e++) { p[e] = expf(l[e] - mx); se += p[e]; }
    float logz = logf(se) + mx;
    int e0 = 0; float b0 = p[0];
#pragma unroll
    for (int e = 1; e < E_NUM; e++) if (p[e] > b0) { b0 = p[e]; e0 = e; }
    int e1 = -1; float b1 = -1.f;
#pragma unroll
    for (int e = 0; e < E_NUM; e++) if (e != e0 && p[e] > b1) { b1 = p[e]; e1 = e; }
    float w0 = b0 / se, w1 = b1 / se;
    if (lane == 0) {
      TopK tk; tk.e0 = e0; tk.e1 = e1; tk.w0 = w0; tk.w1 = w1;
      topk[t] = tk;
      atomicAdd(&counts[e0], 1);        // rank-0 count
      atomicAdd(&counts[8 + e1], 1);    // rank-1 count
      zacc += logz * logz;
      c0 += (e0 == 0 || e1 == 0) ? 1.f : 0.f;
      c1 += (e0 == 1 || e1 == 1) ? 1.f : 0.f;
      s0 += w0; s1 += w1;
    }
  }
  if (lane == 0) {
    atomicAdd(&scal[0], zacc);
    atomicAdd(&scal[1], c0);
    atomicAdd(&scal[2], c1);
    atomicAdd(&scal[3], s0);
    atomicAdd(&scal[4], s1);
  }
}

// ---------------- offsets padded to 128 rows per (rank, expert); fixed rank regions
__global__ void scan_kernel(const int* __restrict__ counts, int* __restrict__ po,
                            int* __restrict__ tile_expert) {
  if (threadIdx.x == 0) {
    for (int r = 0; r < 2; r++) {
      int off = 0, ti = 0;
      for (int e = 0; e < E_NUM; e++) {
        po[r * 8 + e] = r * TILES_PER_RANK * 128 + off;
        int nt = (counts[r * 8 + e] + 127) >> 7;
        for (int j = 0; j < nt; j++) tile_expert[r * TILES_PER_RANK + ti++] = e;
        off += nt << 7;
      }
      while (ti < TILES_PER_RANK) tile_expert[r * TILES_PER_RANK + ti++] = -1;
    }
  }
}

__global__ __launch_bounds__(256) void assign_kernel(
    const TopK* __restrict__ topk, const int* __restrict__ po,
    int* __restrict__ cursors, int* __restrict__ pair_token,
    float* __restrict__ pair_w) {
  int t = blockIdx.x * 256 + threadIdx.x;
  if (t >= T_TOKENS) return;
  TopK tk = topk[t];
  int p0 = po[tk.e0] + atomicAdd(&cursors[tk.e0], 1);
  pair_token[p0] = t; pair_w[p0] = tk.w0;
  int p1 = po[8 + tk.e1] + atomicAdd(&cursors[8 + tk.e1], 1);
  pair_token[p1] = t; pair_w[p1] = tk.w1;
}

// ---------------- grouped GEMM, 128x128 tile, 16x16x32 bf16 MFMA, 2-phase dbuf
// MODE 0: hmid[p,:] = gelu(xb[tok(p),:] @ W1t[e]^T)            (K=1024, N=2048)
// MODE 1: out[tok(p),:] = w(p) * (hmid[p,:] @ W2t[e]^T)  store (K=2048, N=1024)
// MODE 2: out[tok(p),:] += w(p) * (hmid[p,:] @ W2t[e]^T) RMW   (K=2048, N=1024)
template <int MODE, int K, int N, int NT>
__global__ __launch_bounds__(256, 2) void moe_gemm(
    const unsigned short* __restrict__ A, const unsigned short* __restrict__ Bt,
    const int* __restrict__ pair_token, const float* __restrict__ pair_w,
    const int* __restrict__ tile_expert, int tile_base,
    unsigned short* __restrict__ hmid, float* __restrict__ outp) {
  constexpr int NBN = N / 128;
  constexpr int NBLK = NBN * NT;
  // bijective XCD-chunked remap (NBLK % 8 == 0 by construction)
  int l = blockIdx.x;
  int c = (l & 7) * (NBLK / 8) + (l >> 3);
  int mt = tile_base + (c % NT);   // m-tile fast-varying: consecutive blocks share B n-panel
  int nb = c / NT;
  int e = tile_expert[mt];
  if (e < 0) return;
  int m0 = mt << 7;
  int n0 = nb << 7;
  __shared__ __align__(16) unsigned short As[2][128 * 32];
  __shared__ __align__(16) unsigned short Bs[2][128 * 32];
  int tid = threadIdx.x, lane = tid & 63, wid = tid >> 6;
  int wm = wid >> 1, wn = wid & 1;
  int lo = lane & 15, hi = lane >> 4;
  int hi8 = hi * 8;

  // staging: thread tid owns 16B chunk tid (rows 0-63) and tid+256 (rows 64-127)
  int rA = tid >> 2;              // row 0..63
  int kof = (tid & 3) * 8;        // k element offset within 32
  size_t aOff1, aOff2;
  if (MODE == 0) {
    int t1 = pair_token[m0 + rA];      if (t1 < 0) t1 = 0;
    int t2 = pair_token[m0 + rA + 64]; if (t2 < 0) t2 = 0;
    aOff1 = (size_t)t1 * K + kof;
    aOff2 = (size_t)t2 * K + kof;
  } else {
    aOff1 = (size_t)(m0 + rA) * K + kof;
    aOff2 = (size_t)(m0 + rA + 64) * K + kof;
  }
  const unsigned short* aP1 = A + aOff1;
  const unsigned short* aP2 = A + aOff2;
  const unsigned short* bP1 = Bt + ((size_t)e * N + n0 + rA) * K + kof;
  const unsigned short* bP2 = bP1 + (size_t)64 * K;
  int sdst = wid * 512;           // wave-uniform LDS base (+ lane*16B implicit)

#define STAGE(bsel)                                        \
  do {                                                     \
    unsigned short* asd = &As[bsel][sdst];                 \
    unsigned short* bsd = &Bs[bsel][sdst];                 \
    gload_lds16(aP1, asd);                                 \
    gload_lds16(aP2, asd + 2048);                          \
    gload_lds16(bP1, bsd);                                 \
    gload_lds16(bP2, bsd + 2048);                          \
    aP1 += 32; aP2 += 32; bP1 += 32; bP2 += 32;            \
  } while (0)

  f32x4 acc[4][4];
#pragma unroll
  for (int i = 0; i < 4; i++)
#pragma unroll
    for (int j = 0; j < 4; j++) acc[i][j] = (f32x4){0.f, 0.f, 0.f, 0.f};

  STAGE(0);
  __syncthreads();            // drain tile-0 loads
  int buf = 0;
  for (int k0 = 0; k0 < K; k0 += 32) {
    if (k0 + 32 < K) STAGE(buf ^ 1);   // issue next tile BEFORE compute
    bf16x8 af[4], bfv[4];
#pragma unroll
    for (int mf = 0; mf < 4; mf++)
      af[mf] = *(const bf16x8*)&As[buf][(wm * 64 + mf * 16 + lo) * 32 + hi8];
#pragma unroll
    for (int nf = 0; nf < 4; nf++)
      bfv[nf] = *(const bf16x8*)&Bs[buf][(wn * 64 + nf * 16 + lo) * 32 + hi8];
#pragma unroll
    for (int mf = 0; mf < 4; mf++)
#pragma unroll
      for (int nf = 0; nf < 4; nf++)
        // swapped operands: D[row = n-col = 4*hi+r][col = token = lo]
        acc[mf][nf] = __builtin_amdgcn_mfma_f32_16x16x32_bf16(
            bfv[nf], af[mf], acc[mf][nf], 0, 0, 0);
    __syncthreads();          // drains next-tile vmcnt + this-tile lgkm, one barrier
    buf ^= 1;
  }
#undef STAGE

  if (MODE == 0) {
#pragma unroll
    for (int mf = 0; mf < 4; mf++) {
      size_t p = m0 + wm * 64 + mf * 16 + lo;
#pragma unroll
      for (int nf = 0; nf < 4; nf++) {
        int f = n0 + wn * 64 + nf * 16 + hi * 4;
        us4 pk;
#pragma unroll
        for (int r = 0; r < 4; r++) {
          float v = acc[mf][nf][r];
          // tanh-form gelu: x * sigmoid(1.5957691*(x + 0.044715 x^3))
          float u = fmaf(0.044715f * v * v, v, v);
          float s = 1.f / (1.f + __expf(-1.5957691216057308f * u));
          pk[r] = f2bf(v * s);
        }
        *(us4*)&hmid[p * (size_t)N + f] = pk;
      }
    }
  } else {
#pragma unroll
    for (int mf = 0; mf < 4; mf++) {
      int p = m0 + wm * 64 + mf * 16 + lo;
      int t = pair_token[p];
      if (t < 0) continue;
      float w = pair_w[p];
      float* orow = outp + (size_t)t * N;
#pragma unroll
      for (int nf = 0; nf < 4; nf++) {
        int h = n0 + wn * 64 + nf * 16 + hi * 4;
        f32x4 v;
#pragma unroll
        for (int r = 0; r < 4; r++) v[r] = w * acc[mf][nf][r];
        if (MODE == 2) v += *(const f32x4*)&orow[h];   // non-atomic RMW: t unique per dispatch
        *(f32x4*)&orow[h] = v;
      }
    }
  }
}

__global__ void finalize_kernel(const float* __restrict__ scal,
                                float* __restrict__ outTail) {
  if (threadIdx.x == 0 && blockIdx.x == 0) {
    float invT = 1.f / (float)T_TOKENS;
    outTail[0] = scal[0] * invT;  // z_loss
    float tpe0 = scal[1] * invT, tpe1 = scal[2] * invT;
    float rp0 = scal[3] * invT, rp1 = scal[4] * invT;
    outTail[1] = (tpe0 * rp0 + tpe1 * rp1) * 0.5f * 4.f;  // aux (K=2 one_hot path)
  }
}

extern "C" void kernel_launch(void* const* d_in, const int* in_sizes, int n_in,
                              void* d_out, int out_size, void* d_ws, size_t ws_size,
                              hipStream_t stream) {
  const float* x  = (const float*)d_in[0];
  const float* Wg = (const float*)d_in[1];
  const float* W1 = (const float*)d_in[2];
  const float* W2 = (const float*)d_in[3];
  float* outp = (float*)d_out;

  char* w = (char*)d_ws;
  auto alloc = [&](size_t b) { char* p = w; w += (b + 511) & ~(size_t)511; return p; };
  float* scal        = (float*)alloc(32);
  int*   counts      = (int*)alloc(64);
  int*   cursors     = (int*)alloc(64);
  int*   po          = (int*)alloc(64);
  int*   tile_expert = (int*)alloc(TOT_TILES * 4);
  TopK*  topk        = (TopK*)alloc((size_t)T_TOKENS * sizeof(TopK));
  int*   pair_token  = (int*)alloc((size_t)MAX_PAIRS * 4);
  float* pair_w      = (float*)alloc((size_t)MAX_PAIRS * 4);
  unsigned short* xb   = (unsigned short*)alloc((size_t)T_TOKENS * H_DIM * 2);
  unsigned short* w1t  = (unsigned short*)alloc((size_t)E_NUM * F_DIM * H_DIM * 2);
  unsigned short* w2t  = (unsigned short*)alloc((size_t)E_NUM * H_DIM * F_DIM * 2);
  unsigned short* hmid = (unsigned short*)alloc((size_t)MAX_PAIRS * F_DIM * 2);

  hipMemsetAsync(scal, 0, 32, stream);
  hipMemsetAsync(counts, 0, 64, stream);
  hipMemsetAsync(cursors, 0, 64, stream);
  hipMemsetAsync(pair_token, 0xFF, (size_t)MAX_PAIRS * 4, stream);  // -1

  dim3 b256(256);
  // W1 [E][H][F] -> w1t [E][F][H]; W2 [E][F][H] -> w2t [E][H][F]
  transpose_cast<<<dim3(F_DIM / 64, H_DIM / 64, E_NUM), b256, 0, stream>>>(W1, w1t, H_DIM, F_DIM);
  transpose_cast<<<dim3(H_DIM / 64, F_DIM / 64, E_NUM), b256, 0, stream>>>(W2, w2t, F_DIM, H_DIM);
  router_kernel<<<512, b256, 0, stream>>>(x, Wg, xb, topk, counts, scal);
  scan_kernel<<<1, 64, 0, stream>>>(counts, po, tile_expert);
  assign_kernel<<<T_TOKENS / 256, b256, 0, stream>>>(topk, po, cursors, pair_token, pair_w);
  // GEMM1 over both rank regions (272 tiles)
  moe_gemm<0, H_DIM, F_DIM, TOT_TILES><<<dim3((F_DIM / 128) * TOT_TILES), b256, 0, stream>>>(
      xb, w1t, pair_token, pair_w, tile_expert, 0, hmid, nullptr);
  // GEMM2 rank-0: plain store (every token exactly once)
  moe_gemm<1, F_DIM, H_DIM, TILES_PER_RANK><<<dim3((H_DIM / 128) * TILES_PER_RANK), b256, 0, stream>>>(
      hmid, w2t, pair_token, pair_w, tile_expert, 0, nullptr, outp);
  // GEMM2 rank-1: non-atomic RMW add (every token exactly once)
  moe_gemm<2, F_DIM, H_DIM, TILES_PER_RANK><<<dim3((H_DIM / 128) * TILES_PER_RANK), b256, 0, stream>>>(
      hmid, w2t, pair_token, pair_w, tile_expert, TILES_PER_RANK, nullptr, outp);
  finalize_kernel<<<1, 64, 0, stream>>>(scal, outp + (size_t)T_TOKENS * H_DIM);
}

// Round 3
// 772.203 us; speedup vs baseline: 1.7523x; 1.4068x over previous
//
#include <hip/hip_runtime.h>
#include <math.h>

#define T_TOKENS 16384
#define H_DIM 1024
#define F_DIM 2048
#define E_NUM 8
#define TILES_PER_RANK 136             // 16384/128 + 8 pad tiles (per rank)
#define TOT_TILES (2 * TILES_PER_RANK) // 272
#define MAX_PAIRS (TOT_TILES * 128)    // 34816

typedef __attribute__((ext_vector_type(8))) short bf16x8;
typedef __attribute__((ext_vector_type(4))) float f32x4;
typedef __attribute__((ext_vector_type(4))) unsigned short us4;

struct TopK { int e0, e1; float w0, w1; };

__device__ __forceinline__ unsigned short f2bf(float f) {
  unsigned int u = __float_as_uint(f);
  u = (u + 0x7fffu + ((u >> 16) & 1u)) >> 16;
  return (unsigned short)u;
}

__device__ __forceinline__ void gload_lds16(const void* g, void* l) {
  __builtin_amdgcn_global_load_lds(
      (const __attribute__((address_space(1))) void*)g,
      (__attribute__((address_space(3))) void*)l, 16, 0, 0);
}

// ---------------- cast + transpose weights: in [E][R][C] f32 -> out [E][C][R] bf16
// 64x64 tiles; float4 loads, us4 transposed stores via padded LDS tile.
__global__ __launch_bounds__(256) void transpose_cast(
    const float* __restrict__ in, unsigned short* __restrict__ out, int R, int C) {
  __shared__ float tile[64][65];
  int e = blockIdx.z;
  int r0 = blockIdx.y * 64, c0 = blockIdx.x * 64;
  int tid = threadIdx.x;
  const float* src = in + ((size_t)e * R + r0) * C + c0;
#pragma unroll
  for (int p = 0; p < 4; p++) {
    int id = p * 256 + tid;             // 0..1023 float4-chunks
    int row = id >> 4, c4 = (id & 15) * 4;
    float4 v = *(const float4*)&src[(size_t)row * C + c4];
    tile[row][c4 + 0] = v.x; tile[row][c4 + 1] = v.y;
    tile[row][c4 + 2] = v.z; tile[row][c4 + 3] = v.w;
  }
  __syncthreads();
  unsigned short* dst = out + ((size_t)e * C + c0) * R + r0;
#pragma unroll
  for (int p = 0; p < 4; p++) {
    int id = p * 256 + tid;
    int c = id >> 4, r4 = (id & 15) * 4;
    us4 pk;
#pragma unroll
    for (int j = 0; j < 4; j++) pk[j] = f2bf(tile[r4 + j][c]);
    *(us4*)&dst[(size_t)c * R + r4] = pk;
  }
}

// ---------------- router: logits (f32), softmax, top-2, losses, counts, x->bf16
// 1024 blocks x 4 waves, 4 tokens per wave. float4 loads, us4 bf16 stores.
__global__ __launch_bounds__(256) void router_kernel(
    const float* __restrict__ x, const float* __restrict__ Wg,
    unsigned short* __restrict__ xb, TopK* __restrict__ topk,
    int* __restrict__ counts, float* __restrict__ scal) {
  __shared__ float wg[E_NUM][H_DIM];   // [e][h], 32KB
  __shared__ int cnt[16];
  __shared__ float sred[4][5];
  int tid = threadIdx.x;
  if (tid < 16) cnt[tid] = 0;
  for (int i = tid; i < E_NUM * H_DIM; i += 256) wg[i & 7][i >> 3] = Wg[i];
  __syncthreads();
  int lane = tid & 63, wid = tid >> 6;
  float zacc = 0.f, c0 = 0.f, c1 = 0.f, s0 = 0.f, s1 = 0.f;
  int wgid = blockIdx.x * 4 + wid;      // 0..4095
#pragma unroll
  for (int it = 0; it < 4; ++it) {
    int t = wgid + it * 4096;
    const float4* xr = (const float4*)(x + (size_t)t * H_DIM);
    us4* xbr = (us4*)(xb + (size_t)t * H_DIM);
    float l[E_NUM];
#pragma unroll
    for (int e = 0; e < E_NUM; e++) l[e] = 0.f;
#pragma unroll
    for (int i = 0; i < 4; i++) {
      int j = i * 64 + lane;            // float4 index within row
      float4 v = xr[j];
      us4 pk;
      pk[0] = f2bf(v.x); pk[1] = f2bf(v.y); pk[2] = f2bf(v.z); pk[3] = f2bf(v.w);
      xbr[j] = pk;
      int h = j * 4;
#pragma unroll
      for (int e = 0; e < E_NUM; e++) {
        const f32x4 wv = *(const f32x4*)&wg[e][h];   // 16B-aligned, 2-way bank = free
        l[e] = fmaf(v.x, wv[0], l[e]);
        l[e] = fmaf(v.y, wv[1], l[e]);
        l[e] = fmaf(v.z, wv[2], l[e]);
        l[e] = fmaf(v.w, wv[3], l[e]);
      }
    }
#pragma unroll
    for (int off = 32; off > 0; off >>= 1) {
#pragma unroll
      for (int e = 0; e < E_NUM; e++) l[e] += __shfl_xor(l[e], off, 64);
    }
    if (lane == 0) {
      float mx = l[0];
#pragma unroll
      for (int e = 1; e < E_NUM; e++) mx = fmaxf(mx, l[e]);
      float p[E_NUM]; float se = 0.f;
#pragma unroll
      for (int e = 0; e < E_NUM; e++) { p[e] = expf(l[e] - mx); se += p[e]; }
      float logz = logf(se) + mx;
      int e0 = 0; float b0 = p[0];
#pragma unroll
      for (int e = 1; e < E_NUM; e++) if (p[e] > b0) { b0 = p[e]; e0 = e; }
      int e1 = -1; float b1 = -1.f;
#pragma unroll
      for (int e = 0; e < E_NUM; e++) if (e != e0 && p[e] > b1) { b1 = p[e]; e1 = e; }
      float w0 = b0 / se, w1 = b1 / se;
      TopK tk; tk.e0 = e0; tk.e1 = e1; tk.w0 = w0; tk.w1 = w1;
      topk[t] = tk;
      atomicAdd(&cnt[e0], 1);           // LDS histogram (rank 0)
      atomicAdd(&cnt[8 + e1], 1);       // LDS histogram (rank 1)
      zacc += logz * logz;
      c0 += (e0 == 0 || e1 == 0) ? 1.f : 0.f;
      c1 += (e0 == 1 || e1 == 1) ? 1.f : 0.f;
      s0 += w0; s1 += w1;
    }
  }
  if (lane == 0) {
    sred[wid][0] = zacc; sred[wid][1] = c0; sred[wid][2] = c1;
    sred[wid][3] = s0;   sred[wid][4] = s1;
  }
  __syncthreads();
  if (tid == 0) {
    float a[5] = {0.f, 0.f, 0.f, 0.f, 0.f};
    for (int w2 = 0; w2 < 4; w2++)
      for (int k = 0; k < 5; k++) a[k] += sred[w2][k];
    for (int k = 0; k < 5; k++) atomicAdd(&scal[k], a[k]);
  }
  if (tid < 16 && cnt[tid]) atomicAdd(&counts[tid], cnt[tid]);
}

// ---------------- offsets padded to 128 rows per (rank, expert); fixed rank regions
__global__ void scan_kernel(const int* __restrict__ counts, int* __restrict__ po,
                            int* __restrict__ tile_expert) {
  if (threadIdx.x == 0) {
    for (int r = 0; r < 2; r++) {
      int off = 0, ti = 0;
      for (int e = 0; e < E_NUM; e++) {
        po[r * 8 + e] = r * TILES_PER_RANK * 128 + off;
        int nt = (counts[r * 8 + e] + 127) >> 7;
        for (int j = 0; j < nt; j++) tile_expert[r * TILES_PER_RANK + ti++] = e;
        off += nt << 7;
      }
      while (ti < TILES_PER_RANK) tile_expert[r * TILES_PER_RANK + ti++] = -1;
    }
  }
}

__global__ __launch_bounds__(256) void assign_kernel(
    const TopK* __restrict__ topk, const int* __restrict__ po,
    int* __restrict__ cursors, int* __restrict__ pair_token,
    float* __restrict__ pair_w) {
  int t = blockIdx.x * 256 + threadIdx.x;
  if (t >= T_TOKENS) return;
  TopK tk = topk[t];
  int p0 = po[tk.e0] + atomicAdd(&cursors[tk.e0], 1);
  pair_token[p0] = t; pair_w[p0] = tk.w0;
  int p1 = po[8 + tk.e1] + atomicAdd(&cursors[8 + tk.e1], 1);
  pair_token[p1] = t; pair_w[p1] = tk.w1;
}

// ---------------- grouped GEMM, 128x128 tile, 16x16x32 bf16 MFMA, 2-phase dbuf
// MODE 0: hmid[p,:] = gelu(xb[tok(p),:] @ W1t[e]^T)            (K=1024, N=2048)
// MODE 1: out[tok(p),:] = w(p) * (hmid[p,:] @ W2t[e]^T)  store (K=2048, N=1024)
// MODE 2: out[tok(p),:] += w(p) * (hmid[p,:] @ W2t[e]^T) RMW   (K=2048, N=1024)
template <int MODE, int K, int N, int NT>
__global__ __launch_bounds__(256, 2) void moe_gemm(
    const unsigned short* __restrict__ A, const unsigned short* __restrict__ Bt,
    const int* __restrict__ pair_token, const float* __restrict__ pair_w,
    const int* __restrict__ tile_expert, int tile_base,
    unsigned short* __restrict__ hmid, float* __restrict__ outp) {
  constexpr int NBN = N / 128;
  constexpr int NBLK = NBN * NT;
  // bijective XCD-chunked remap (NBLK % 8 == 0 by construction)
  int l = blockIdx.x;
  int c = (l & 7) * (NBLK / 8) + (l >> 3);
  int mt = tile_base + (c % NT);   // m-tile fast-varying: consecutive blocks share B n-panel
  int nb = c / NT;
  int e = tile_expert[mt];
  if (e < 0) return;
  int m0 = mt << 7;
  int n0 = nb << 7;
  __shared__ __align__(16) unsigned short As[2][128 * 32];
  __shared__ __align__(16) unsigned short Bs[2][128 * 32];
  int tid = threadIdx.x, lane = tid & 63, wid = tid >> 6;
  int wm = wid >> 1, wn = wid & 1;
  int lo = lane & 15, hi = lane >> 4;
  int hi8 = hi * 8;

  // staging: thread tid owns 16B chunk tid (rows 0-63) and tid+256 (rows 64-127)
  int rA = tid >> 2;              // row 0..63
  int kof = (tid & 3) * 8;        // k element offset within 32
  size_t aOff1, aOff2;
  if (MODE == 0) {
    int t1 = pair_token[m0 + rA];      if (t1 < 0) t1 = 0;
    int t2 = pair_token[m0 + rA + 64]; if (t2 < 0) t2 = 0;
    aOff1 = (size_t)t1 * K + kof;
    aOff2 = (size_t)t2 * K + kof;
  } else {
    aOff1 = (size_t)(m0 + rA) * K + kof;
    aOff2 = (size_t)(m0 + rA + 64) * K + kof;
  }
  const unsigned short* aP1 = A + aOff1;
  const unsigned short* aP2 = A + aOff2;
  const unsigned short* bP1 = Bt + ((size_t)e * N + n0 + rA) * K + kof;
  const unsigned short* bP2 = bP1 + (size_t)64 * K;
  int sdst = wid * 512;           // wave-uniform LDS base (+ lane*16B implicit)

#define STAGE(bsel)                                        \
  do {                                                     \
    unsigned short* asd = &As[bsel][sdst];                 \
    unsigned short* bsd = &Bs[bsel][sdst];                 \
    gload_lds16(aP1, asd);                                 \
    gload_lds16(aP2, asd + 2048);                          \
    gload_lds16(bP1, bsd);                                 \
    gload_lds16(bP2, bsd + 2048);                          \
    aP1 += 32; aP2 += 32; bP1 += 32; bP2 += 32;            \
  } while (0)

  f32x4 acc[4][4];
#pragma unroll
  for (int i = 0; i < 4; i++)
#pragma unroll
    for (int j = 0; j < 4; j++) acc[i][j] = (f32x4){0.f, 0.f, 0.f, 0.f};

  STAGE(0);
  __syncthreads();            // drain tile-0 loads
  int buf = 0;
  for (int k0 = 0; k0 < K; k0 += 32) {
    if (k0 + 32 < K) STAGE(buf ^ 1);   // issue next tile BEFORE compute
    bf16x8 af[4], bfv[4];
#pragma unroll
    for (int mf = 0; mf < 4; mf++)
      af[mf] = *(const bf16x8*)&As[buf][(wm * 64 + mf * 16 + lo) * 32 + hi8];
#pragma unroll
    for (int nf = 0; nf < 4; nf++)
      bfv[nf] = *(const bf16x8*)&Bs[buf][(wn * 64 + nf * 16 + lo) * 32 + hi8];
#pragma unroll
    for (int mf = 0; mf < 4; mf++)
#pragma unroll
      for (int nf = 0; nf < 4; nf++)
        // swapped operands: D[row = n-col = 4*hi+r][col = token = lo]
        acc[mf][nf] = __builtin_amdgcn_mfma_f32_16x16x32_bf16(
            bfv[nf], af[mf], acc[mf][nf], 0, 0, 0);
    __syncthreads();          // drains next-tile vmcnt + this-tile lgkm, one barrier
    buf ^= 1;
  }
#undef STAGE

  if (MODE == 0) {
#pragma unroll
    for (int mf = 0; mf < 4; mf++) {
      size_t p = m0 + wm * 64 + mf * 16 + lo;
#pragma unroll
      for (int nf = 0; nf < 4; nf++) {
        int f = n0 + wn * 64 + nf * 16 + hi * 4;
        us4 pk;
#pragma unroll
        for (int r = 0; r < 4; r++) {
          float v = acc[mf][nf][r];
          // tanh-form gelu: x * sigmoid(1.5957691*(x + 0.044715 x^3))
          float u = fmaf(0.044715f * v * v, v, v);
          float s = 1.f / (1.f + __expf(-1.5957691216057308f * u));
          pk[r] = f2bf(v * s);
        }
        *(us4*)&hmid[p * (size_t)N + f] = pk;
      }
    }
  } else {
#pragma unroll
    for (int mf = 0; mf < 4; mf++) {
      int p = m0 + wm * 64 + mf * 16 + lo;
      int t = pair_token[p];
      if (t < 0) continue;
      float w = pair_w[p];
      float* orow = outp + (size_t)t * N;
#pragma unroll
      for (int nf = 0; nf < 4; nf++) {
        int h = n0 + wn * 64 + nf * 16 + hi * 4;
        f32x4 v;
#pragma unroll
        for (int r = 0; r < 4; r++) v[r] = w * acc[mf][nf][r];
        if (MODE == 2) v += *(const f32x4*)&orow[h];   // non-atomic RMW: t unique per dispatch
        *(f32x4*)&orow[h] = v;
      }
    }
  }
}

__global__ void finalize_kernel(const float* __restrict__ scal,
                                float* __restrict__ outTail) {
  if (threadIdx.x == 0 && blockIdx.x == 0) {
    float invT = 1.f / (float)T_TOKENS;
    outTail[0] = scal[0] * invT;  // z_loss
    float tpe0 = scal[1] * invT, tpe1 = scal[2] * invT;
    float rp0 = scal[3] * invT, rp1 = scal[4] * invT;
    outTail[1] = (tpe0 * rp0 + tpe1 * rp1) * 0.5f * 4.f;  // aux (K=2 one_hot path)
  }
}

extern "C" void kernel_launch(void* const* d_in, const int* in_sizes, int n_in,
                              void* d_out, int out_size, void* d_ws, size_t ws_size,
                              hipStream_t stream) {
  const float* x  = (const float*)d_in[0];
  const float* Wg = (const float*)d_in[1];
  const float* W1 = (const float*)d_in[2];
  const float* W2 = (const float*)d_in[3];
  float* outp = (float*)d_out;

  char* w = (char*)d_ws;
  auto alloc = [&](size_t b) { char* p = w; w += (b + 511) & ~(size_t)511; return p; };
  float* scal        = (float*)alloc(32);
  int*   counts      = (int*)alloc(64);
  int*   cursors     = (int*)alloc(64);
  int*   po          = (int*)alloc(64);
  int*   tile_expert = (int*)alloc(TOT_TILES * 4);
  TopK*  topk        = (TopK*)alloc((size_t)T_TOKENS * sizeof(TopK));
  int*   pair_token  = (int*)alloc((size_t)MAX_PAIRS * 4);
  float* pair_w      = (float*)alloc((size_t)MAX_PAIRS * 4);
  unsigned short* xb   = (unsigned short*)alloc((size_t)T_TOKENS * H_DIM * 2);
  unsigned short* w1t  = (unsigned short*)alloc((size_t)E_NUM * F_DIM * H_DIM * 2);
  unsigned short* w2t  = (unsigned short*)alloc((size_t)E_NUM * H_DIM * F_DIM * 2);
  unsigned short* hmid = (unsigned short*)alloc((size_t)MAX_PAIRS * F_DIM * 2);

  hipMemsetAsync(scal, 0, 32, stream);
  hipMemsetAsync(counts, 0, 64, stream);
  hipMemsetAsync(cursors, 0, 64, stream);
  hipMemsetAsync(pair_token, 0xFF, (size_t)MAX_PAIRS * 4, stream);  // -1

  dim3 b256(256);
  // W1 [E][H][F] -> w1t [E][F][H]; W2 [E][F][H] -> w2t [E][H][F]
  transpose_cast<<<dim3(F_DIM / 64, H_DIM / 64, E_NUM), b256, 0, stream>>>(W1, w1t, H_DIM, F_DIM);
  transpose_cast<<<dim3(H_DIM / 64, F_DIM / 64, E_NUM), b256, 0, stream>>>(W2, w2t, F_DIM, H_DIM);
  router_kernel<<<1024, b256, 0, stream>>>(x, Wg, xb, topk, counts, scal);
  scan_kernel<<<1, 64, 0, stream>>>(counts, po, tile_expert);
  assign_kernel<<<T_TOKENS / 256, b256, 0, stream>>>(topk, po, cursors, pair_token, pair_w);
  // GEMM1 over both rank regions (272 tiles)
  moe_gemm<0, H_DIM, F_DIM, TOT_TILES><<<dim3((F_DIM / 128) * TOT_TILES), b256, 0, stream>>>(
      xb, w1t, pair_token, pair_w, tile_expert, 0, hmid, nullptr);
  // GEMM2 rank-0: plain store (every token exactly once)
  moe_gemm<1, F_DIM, H_DIM, TILES_PER_RANK><<<dim3((H_DIM / 128) * TILES_PER_RANK), b256, 0, stream>>>(
      hmid, w2t, pair_token, pair_w, tile_expert, 0, nullptr, outp);
  // GEMM2 rank-1: non-atomic RMW add (every token exactly once)
  moe_gemm<2, F_DIM, H_DIM, TILES_PER_RANK><<<dim3((H_DIM / 128) * TILES_PER_RANK), b256, 0, stream>>>(
      hmid, w2t, pair_token, pair_w, tile_expert, TILES_PER_RANK, nullptr, outp);
  finalize_kernel<<<1, 64, 0, stream>>>(scal, outp + (size_t)T_TOKENS * H_DIM);
}

// Round 5
// 735.395 us; speedup vs baseline: 1.8400x; 1.0501x over previous
//
#include <hip/hip_runtime.h>
#include <math.h>

#define T_TOKENS 16384
#define H_DIM 1024
#define F_DIM 2048
#define E_NUM 8
#define TPR 72                      // 256-row tiles per rank (16384/256 + 8 pad)
#define TOT_T (2 * TPR)             // 144
#define MAX_PAIRS (TOT_T * 256)     // 36864

typedef __attribute__((ext_vector_type(8))) short bf16x8;
typedef __attribute__((ext_vector_type(4))) float f32x4;
typedef __attribute__((ext_vector_type(4))) unsigned short us4;

struct TopK { int e0, e1; float w0, w1; };

__device__ __forceinline__ unsigned short f2bf(float f) {
  unsigned int u = __float_as_uint(f);
  u = (u + 0x7fffu + ((u >> 16) & 1u)) >> 16;
  return (unsigned short)u;
}

__device__ __forceinline__ void gload_lds16(const void* g, void* l) {
  __builtin_amdgcn_global_load_lds(
      (const __attribute__((address_space(1))) void*)g,
      (__attribute__((address_space(3))) void*)l, 16, 0, 0);
}

// ---------------- cast + transpose weights: in [E][R][C] f32 -> out [E][C][R] bf16
__global__ __launch_bounds__(256) void transpose_cast(
    const float* __restrict__ in, unsigned short* __restrict__ out, int R, int C) {
  __shared__ float tile[64][65];
  int e = blockIdx.z;
  int r0 = blockIdx.y * 64, c0 = blockIdx.x * 64;
  int tid = threadIdx.x;
  const float* src = in + ((size_t)e * R + r0) * C + c0;
#pragma unroll
  for (int p = 0; p < 4; p++) {
    int id = p * 256 + tid;
    int row = id >> 4, c4 = (id & 15) * 4;
    float4 v = *(const float4*)&src[(size_t)row * C + c4];
    tile[row][c4 + 0] = v.x; tile[row][c4 + 1] = v.y;
    tile[row][c4 + 2] = v.z; tile[row][c4 + 3] = v.w;
  }
  __syncthreads();
  unsigned short* dst = out + ((size_t)e * C + c0) * R + r0;
#pragma unroll
  for (int p = 0; p < 4; p++) {
    int id = p * 256 + tid;
    int c = id >> 4, r4 = (id & 15) * 4;
    us4 pk;
#pragma unroll
    for (int j = 0; j < 4; j++) pk[j] = f2bf(tile[r4 + j][c]);
    *(us4*)&dst[(size_t)c * R + r4] = pk;
  }
}

// ---------------- router: logits (f32), softmax, top-2, losses, counts, x->bf16
__global__ __launch_bounds__(256) void router_kernel(
    const float* __restrict__ x, const float* __restrict__ Wg,
    unsigned short* __restrict__ xb, TopK* __restrict__ topk,
    int* __restrict__ counts, float* __restrict__ scal) {
  __shared__ float wg[E_NUM][H_DIM];
  __shared__ int cnt[16];
  __shared__ float sred[4][5];
  int tid = threadIdx.x;
  if (tid < 16) cnt[tid] = 0;
  for (int i = tid; i < E_NUM * H_DIM; i += 256) wg[i & 7][i >> 3] = Wg[i];
  __syncthreads();
  int lane = tid & 63, wid = tid >> 6;
  float zacc = 0.f, c0 = 0.f, c1 = 0.f, s0 = 0.f, s1 = 0.f;
  int wgid = blockIdx.x * 4 + wid;
#pragma unroll
  for (int it = 0; it < 4; ++it) {
    int t = wgid + it * 4096;
    const float4* xr = (const float4*)(x + (size_t)t * H_DIM);
    us4* xbr = (us4*)(xb + (size_t)t * H_DIM);
    float l[E_NUM];
#pragma unroll
    for (int e = 0; e < E_NUM; e++) l[e] = 0.f;
#pragma unroll
    for (int i = 0; i < 4; i++) {
      int j = i * 64 + lane;
      float4 v = xr[j];
      us4 pk;
      pk[0] = f2bf(v.x); pk[1] = f2bf(v.y); pk[2] = f2bf(v.z); pk[3] = f2bf(v.w);
      xbr[j] = pk;
      int h = j * 4;
#pragma unroll
      for (int e = 0; e < E_NUM; e++) {
        const f32x4 wv = *(const f32x4*)&wg[e][h];
        l[e] = fmaf(v.x, wv[0], l[e]);
        l[e] = fmaf(v.y, wv[1], l[e]);
        l[e] = fmaf(v.z, wv[2], l[e]);
        l[e] = fmaf(v.w, wv[3], l[e]);
      }
    }
#pragma unroll
    for (int off = 32; off > 0; off >>= 1) {
#pragma unroll
      for (int e = 0; e < E_NUM; e++) l[e] += __shfl_xor(l[e], off, 64);
    }
    if (lane == 0) {
      float mx = l[0];
#pragma unroll
      for (int e = 1; e < E_NUM; e++) mx = fmaxf(mx, l[e]);
      float p[E_NUM]; float se = 0.f;
#pragma unroll
      for (int e = 0; e < E_NUM; e++) { p[e] = expf(l[e] - mx); se += p[e]; }
      float logz = logf(se) + mx;
      int e0 = 0; float b0 = p[0];
#pragma unroll
      for (int e = 1; e < E_NUM; e++) if (p[e] > b0) { b0 = p[e]; e0 = e; }
      int e1 = -1; float b1 = -1.f;
#pragma unroll
      for (int e = 0; e < E_NUM; e++) if (e != e0 && p[e] > b1) { b1 = p[e]; e1 = e; }
      float w0 = b0 / se, w1 = b1 / se;
      TopK tk; tk.e0 = e0; tk.e1 = e1; tk.w0 = w0; tk.w1 = w1;
      topk[t] = tk;
      atomicAdd(&cnt[e0], 1);
      atomicAdd(&cnt[8 + e1], 1);
      zacc += logz * logz;
      c0 += (e0 == 0 || e1 == 0) ? 1.f : 0.f;
      c1 += (e0 == 1 || e1 == 1) ? 1.f : 0.f;
      s0 += w0; s1 += w1;
    }
  }
  if (lane == 0) {
    sred[wid][0] = zacc; sred[wid][1] = c0; sred[wid][2] = c1;
    sred[wid][3] = s0;   sred[wid][4] = s1;
  }
  __syncthreads();
  if (tid == 0) {
    float a[5] = {0.f, 0.f, 0.f, 0.f, 0.f};
    for (int w2 = 0; w2 < 4; w2++)
      for (int k = 0; k < 5; k++) a[k] += sred[w2][k];
    for (int k = 0; k < 5; k++) atomicAdd(&scal[k], a[k]);
  }
  if (tid < 16 && cnt[tid]) atomicAdd(&counts[tid], cnt[tid]);
}

// ---------------- offsets padded to 256 rows per (rank, expert)
__global__ void scan_kernel(const int* __restrict__ counts, int* __restrict__ po,
                            int* __restrict__ tile_expert) {
  if (threadIdx.x == 0) {
    for (int r = 0; r < 2; r++) {
      int off = 0, ti = 0;
      for (int e = 0; e < E_NUM; e++) {
        po[r * 8 + e] = r * TPR * 256 + off;
        int nt = (counts[r * 8 + e] + 255) >> 8;
        for (int j = 0; j < nt; j++) tile_expert[r * TPR + ti++] = e;
        off += nt << 8;
      }
      while (ti < TPR) tile_expert[r * TPR + ti++] = -1;
    }
  }
}

__global__ __launch_bounds__(256) void assign_kernel(
    const TopK* __restrict__ topk, const int* __restrict__ po,
    int* __restrict__ cursors, int* __restrict__ pair_token,
    float* __restrict__ pair_w) {
  int t = blockIdx.x * 256 + threadIdx.x;
  if (t >= T_TOKENS) return;
  TopK tk = topk[t];
  int p0 = po[tk.e0] + atomicAdd(&cursors[tk.e0], 1);
  pair_token[p0] = t; pair_w[p0] = tk.w0;
  int p1 = po[8 + tk.e1] + atomicAdd(&cursors[8 + tk.e1], 1);
  pair_token[p1] = t; pair_w[p1] = tk.w1;
}

// ---------------- grouped GEMM, 256x256 tile, 8 waves, BK=32, counted-vmcnt phases
// MODE 0: hmid[p,:] = gelu(xb[tok(p),:] @ W1t[e]^T)           (K=1024, N=2048)
// MODE 1: out[tok(p),:] = w(p) * (hmid[p,:] @ W2t[e]^T) store (K=2048, N=1024)
// MODE 2: out[tok(p),:] += w(p) * (hmid[p,:] @ W2t[e]^T) RMW  (K=2048, N=1024)
template <int MODE, int K, int N, int NTILES>
__global__ __launch_bounds__(512, 2) void moe_gemm8(
    const unsigned short* __restrict__ A, const unsigned short* __restrict__ Bt,
    const int* __restrict__ pair_token, const float* __restrict__ pair_w,
    const int* __restrict__ tile_expert, int tile_base,
    unsigned short* __restrict__ hmid, float* __restrict__ outp) {
  constexpr int NBN = N / 256;
  constexpr int NBLK = NBN * NTILES;           // % 8 == 0 by construction
  int l = blockIdx.x;
  int c = (l & 7) * (NBLK / 8) + (l >> 3);     // bijective XCD-chunked remap
  int mt = tile_base + (c % NTILES);           // m fast-varying: XCD shares B n-panel
  int nb = c / NTILES;
  int e = tile_expert[mt];
  if (e < 0) return;
  int m0 = mt << 8, n0 = nb << 8;

  __shared__ __align__(16) unsigned short lds[32768];  // 64KB: 2 bufs x [A0 A1 B0 B1]
  int tid = threadIdx.x, lane = tid & 63, wid = tid >> 6;
  int wm = wid >> 2, wn = wid & 3;             // 2 x 4 wave grid
  int lo = lane & 15, hi = lane >> 4;

  // ---- stage (write) side: per-thread row + pre-swizzled source chunk ----
  int srow = wid * 16 + (lane >> 2);           // 0..127
  int csrc = (lane & 3) ^ ((lane >> 3) & 3);   // chunk ^ ((row>>1)&3), thread-const
  const unsigned short *pA0, *pA1, *pB0, *pB1;
  if (MODE == 0) {
    int t0 = pair_token[m0 + srow];        if (t0 < 0) t0 = 0;
    int t1 = pair_token[m0 + 128 + srow];  if (t1 < 0) t1 = 0;
    pA0 = A + (size_t)t0 * K + csrc * 8;
    pA1 = A + (size_t)t1 * K + csrc * 8;
  } else {
    pA0 = A + (size_t)(m0 + srow) * K + csrc * 8;
    pA1 = A + (size_t)(m0 + 128 + srow) * K + csrc * 8;
  }
  pB0 = Bt + ((size_t)e * N + n0 + srow) * K + csrc * 8;
  pB1 = pB0 + (size_t)128 * K;
  int sdA = wid * 512;                         // LDS dest base (+lane*16B implicit)

  // ---- read side: swizzled chunk is thread-const too ----
  int ck = (hi ^ ((lo >> 1) & 3)) * 8;
  int aB = wm * 4096 + lo * 32 + ck;
  int bB = 8192 + (wn >> 1) * 4096 + ((wn & 1) * 64 + lo) * 32 + ck;

  f32x4 acc[8][4];
#pragma unroll
  for (int i = 0; i < 8; i++)
#pragma unroll
    for (int j = 0; j < 4; j++) acc[i][j] = (f32x4){0.f, 0.f, 0.f, 0.f};

#define SA(off) do { \
    gload_lds16(pA0, &lds[(off) + sdA]); \
    gload_lds16(pA1, &lds[(off) + 4096 + sdA]); \
    pA0 += 32; pA1 += 32; } while (0)
#define SB(off) do { \
    gload_lds16(pB0, &lds[(off) + 8192 + sdA]); \
    gload_lds16(pB1, &lds[(off) + 12288 + sdA]); \
    pB0 += 32; pB1 += 32; } while (0)
#define BAR() do { asm volatile("s_barrier" ::: "memory"); \
    __builtin_amdgcn_sched_barrier(0); } while (0)
#define VM2() do { asm volatile("s_waitcnt vmcnt(2)" ::: "memory"); \
    __builtin_amdgcn_sched_barrier(0); } while (0)

  // prologue: B(0)->buf0, A(0)->buf0, B(1)->buf1; confirm tile0, keep B(1) in flight
  SB(0); SA(0); SB(16384);
  VM2(); BAR();

  bf16x8 afr[4], bfr[4];
  constexpr int NT = K / 32;
  for (int t = 0; t < NT; ++t) {
    int bo = (t & 1) * 16384;
    int obo = 16384 - bo;
    // ---- phase a: dsr a0-3,b0-3; stage A(t+1)->other buf; 16 MFMA ----
#pragma unroll
    for (int m = 0; m < 4; m++) afr[m] = *(const bf16x8*)&lds[bo + aB + m * 512];
#pragma unroll
    for (int n = 0; n < 4; n++) bfr[n] = *(const bf16x8*)&lds[bo + bB + n * 512];
    SA(obo);
    BAR();
    __builtin_amdgcn_s_setprio(1);
#pragma unroll
    for (int m = 0; m < 4; m++)
#pragma unroll
      for (int n = 0; n < 4; n++)
        acc[m][n] = __builtin_amdgcn_mfma_f32_16x16x32_bf16(bfr[n], afr[m], acc[m][n], 0, 0, 0);
    __builtin_amdgcn_s_setprio(0);
    BAR();
    // ---- phase b: dsr a4-7; stage B(t+2)->current buf; 16 MFMA; vmcnt(2) ----
#pragma unroll
    for (int m = 0; m < 4; m++) afr[m] = *(const bf16x8*)&lds[bo + aB + (4 + m) * 512];
    SB(bo);
    BAR();
    __builtin_amdgcn_s_setprio(1);
#pragma unroll
    for (int m = 0; m < 4; m++)
#pragma unroll
      for (int n = 0; n < 4; n++)
        acc[4 + m][n] = __builtin_amdgcn_mfma_f32_16x16x32_bf16(bfr[n], afr[m], acc[4 + m][n], 0, 0, 0);
    __builtin_amdgcn_s_setprio(0);
    VM2(); BAR();
  }
  // drain all outstanding global_load_lds before LDS teardown / endpgm
  asm volatile("s_waitcnt vmcnt(0)" ::: "memory");
  __builtin_amdgcn_sched_barrier(0);
#undef SA
#undef SB
#undef BAR
#undef VM2

  if (MODE == 0) {
#pragma unroll
    for (int mf = 0; mf < 8; mf++) {
      size_t p = m0 + wm * 128 + mf * 16 + lo;
#pragma unroll
      for (int nf = 0; nf < 4; nf++) {
        int f = n0 + wn * 64 + nf * 16 + hi * 4;
        us4 pk;
#pragma unroll
        for (int r = 0; r < 4; r++) {
          float v = acc[mf][nf][r];
          float u = fmaf(0.044715f * v * v, v, v);
          float s = 1.f / (1.f + __expf(-1.5957691216057308f * u));
          pk[r] = f2bf(v * s);
        }
        *(us4*)&hmid[p * (size_t)N + f] = pk;
      }
    }
  } else {
#pragma unroll
    for (int mf = 0; mf < 8; mf++) {
      int p = m0 + wm * 128 + mf * 16 + lo;
      int t = pair_token[p];
      if (t < 0) continue;
      float w = pair_w[p];
      float* orow = outp + (size_t)t * N;
#pragma unroll
      for (int nf = 0; nf < 4; nf++) {
        int f = n0 + wn * 64 + nf * 16 + hi * 4;
        f32x4 v;
#pragma unroll
        for (int r = 0; r < 4; r++) v[r] = w * acc[mf][nf][r];
        if (MODE == 2) v += *(const f32x4*)&orow[f];   // non-atomic RMW: t unique per dispatch
        *(f32x4*)&orow[f] = v;
      }
    }
  }
}

__global__ void finalize_kernel(const float* __restrict__ scal,
                                float* __restrict__ outTail) {
  if (threadIdx.x == 0 && blockIdx.x == 0) {
    float invT = 1.f / (float)T_TOKENS;
    outTail[0] = scal[0] * invT;  // z_loss
    float tpe0 = scal[1] * invT, tpe1 = scal[2] * invT;
    float rp0 = scal[3] * invT, rp1 = scal[4] * invT;
    outTail[1] = (tpe0 * rp0 + tpe1 * rp1) * 0.5f * 4.f;  // aux (K=2 one_hot path)
  }
}

extern "C" void kernel_launch(void* const* d_in, const int* in_sizes, int n_in,
                              void* d_out, int out_size, void* d_ws, size_t ws_size,
                              hipStream_t stream) {
  const float* x  = (const float*)d_in[0];
  const float* Wg = (const float*)d_in[1];
  const float* W1 = (const float*)d_in[2];
  const float* W2 = (const float*)d_in[3];
  float* outp = (float*)d_out;

  char* w = (char*)d_ws;
  auto alloc = [&](size_t b) { char* p = w; w += (b + 511) & ~(size_t)511; return p; };
  float* scal        = (float*)alloc(32);
  int*   counts      = (int*)alloc(64);
  int*   cursors     = (int*)alloc(64);
  int*   po          = (int*)alloc(64);
  int*   tile_expert = (int*)alloc(TOT_T * 4);
  TopK*  topk        = (TopK*)alloc((size_t)T_TOKENS * sizeof(TopK));
  int*   pair_token  = (int*)alloc((size_t)MAX_PAIRS * 4);
  float* pair_w      = (float*)alloc((size_t)MAX_PAIRS * 4);
  // staged buffers padded +512B (staging prefetch overruns by <~200B)
  unsigned short* xb   = (unsigned short*)alloc((size_t)T_TOKENS * H_DIM * 2 + 512);
  unsigned short* w1t  = (unsigned short*)alloc((size_t)E_NUM * F_DIM * H_DIM * 2 + 512);
  unsigned short* hmid = (unsigned short*)alloc((size_t)MAX_PAIRS * F_DIM * 2 + 512);
  // w2t ALIASES xb (xb is dead after GEMM1; W2 transpose launched after GEMM1).
  // Keeps total workspace ~209 MiB, under the known-good 232.5 MiB of R3.
  unsigned short* w2t  = xb;

  hipMemsetAsync(scal, 0, 32, stream);
  hipMemsetAsync(counts, 0, 64, stream);
  hipMemsetAsync(cursors, 0, 64, stream);
  hipMemsetAsync(pair_token, 0xFF, (size_t)MAX_PAIRS * 4, stream);  // -1

  dim3 b256(256), b512(512);
  // W1 [E][H][F] -> w1t [E][F][H]
  transpose_cast<<<dim3(F_DIM / 64, H_DIM / 64, E_NUM), b256, 0, stream>>>(W1, w1t, H_DIM, F_DIM);
  router_kernel<<<1024, b256, 0, stream>>>(x, Wg, xb, topk, counts, scal);
  scan_kernel<<<1, 64, 0, stream>>>(counts, po, tile_expert);
  assign_kernel<<<T_TOKENS / 256, b256, 0, stream>>>(topk, po, cursors, pair_token, pair_w);
  // GEMM1: hmid = gelu(gather(xb) @ W1t^T), both rank regions, one dispatch
  moe_gemm8<0, H_DIM, F_DIM, TOT_T><<<dim3((F_DIM / 256) * TOT_T), b512, 0, stream>>>(
      xb, w1t, pair_token, pair_w, tile_expert, 0, hmid, nullptr);
  // W2 [E][F][H] -> w2t [E][H][F]  (into xb's space — xb dead now)
  transpose_cast<<<dim3(H_DIM / 64, F_DIM / 64, E_NUM), b256, 0, stream>>>(W2, w2t, F_DIM, H_DIM);
  // GEMM2 rank-0: plain store (every token exactly once)
  moe_gemm8<1, F_DIM, H_DIM, TPR><<<dim3((H_DIM / 256) * TPR), b512, 0, stream>>>(
      hmid, w2t, pair_token, pair_w, tile_expert, 0, nullptr, outp);
  // GEMM2 rank-1: non-atomic RMW add (every token exactly once)
  moe_gemm8<2, F_DIM, H_DIM, TPR><<<dim3((H_DIM / 256) * TPR), b512, 0, stream>>>(
      hmid, w2t, pair_token, pair_w, tile_expert, TPR, nullptr, outp);
  finalize_kernel<<<1, 64, 0, stream>>>(scal, outp + (size_t)T_TOKENS * H_DIM);
}

// Round 6
// 725.818 us; speedup vs baseline: 1.8642x; 1.0132x over previous
//
#include <hip/hip_runtime.h>
#include <math.h>

#define T_TOKENS 16384
#define H_DIM 1024
#define F_DIM 2048
#define E_NUM 8
#define TPR 72                      // 256-row tiles per rank (16384/256 + 8 pad)
#define TOT_T (2 * TPR)             // 144
#define MAX_PAIRS (TOT_T * 256)     // 36864

typedef __attribute__((ext_vector_type(8))) short bf16x8;
typedef __attribute__((ext_vector_type(4))) float f32x4;
typedef __attribute__((ext_vector_type(4))) unsigned short us4;

struct TopK { int e0, e1; float w0, w1; };

__device__ __forceinline__ unsigned short f2bf(float f) {
  unsigned int u = __float_as_uint(f);
  u = (u + 0x7fffu + ((u >> 16) & 1u)) >> 16;
  return (unsigned short)u;
}

__device__ __forceinline__ void gload_lds16(const void* g, void* l) {
  __builtin_amdgcn_global_load_lds(
      (const __attribute__((address_space(1))) void*)g,
      (__attribute__((address_space(3))) void*)l, 16, 0, 0);
}

// ---------------- cast + transpose weights: in [E][R][C] f32 -> out [E][C][R] bf16
__global__ __launch_bounds__(256) void transpose_cast(
    const float* __restrict__ in, unsigned short* __restrict__ out, int R, int C) {
  __shared__ float tile[64][65];
  int e = blockIdx.z;
  int r0 = blockIdx.y * 64, c0 = blockIdx.x * 64;
  int tid = threadIdx.x;
  const float* src = in + ((size_t)e * R + r0) * C + c0;
#pragma unroll
  for (int p = 0; p < 4; p++) {
    int id = p * 256 + tid;
    int row = id >> 4, c4 = (id & 15) * 4;
    float4 v = *(const float4*)&src[(size_t)row * C + c4];
    tile[row][c4 + 0] = v.x; tile[row][c4 + 1] = v.y;
    tile[row][c4 + 2] = v.z; tile[row][c4 + 3] = v.w;
  }
  __syncthreads();
  unsigned short* dst = out + ((size_t)e * C + c0) * R + r0;
#pragma unroll
  for (int p = 0; p < 4; p++) {
    int id = p * 256 + tid;
    int c = id >> 4, r4 = (id & 15) * 4;
    us4 pk;
#pragma unroll
    for (int j = 0; j < 4; j++) pk[j] = f2bf(tile[r4 + j][c]);
    *(us4*)&dst[(size_t)c * R + r4] = pk;
  }
}

// ---------------- router: logits (f32), softmax, top-2, losses, counts, x->bf16
__global__ __launch_bounds__(256) void router_kernel(
    const float* __restrict__ x, const float* __restrict__ Wg,
    unsigned short* __restrict__ xb, TopK* __restrict__ topk,
    int* __restrict__ counts, float* __restrict__ scal) {
  __shared__ float wg[E_NUM][H_DIM];
  __shared__ int cnt[16];
  __shared__ float sred[4][5];
  int tid = threadIdx.x;
  if (tid < 16) cnt[tid] = 0;
  for (int i = tid; i < E_NUM * H_DIM; i += 256) wg[i & 7][i >> 3] = Wg[i];
  __syncthreads();
  int lane = tid & 63, wid = tid >> 6;
  float zacc = 0.f, c0 = 0.f, c1 = 0.f, s0 = 0.f, s1 = 0.f;
  int wgid = blockIdx.x * 4 + wid;
#pragma unroll
  for (int it = 0; it < 4; ++it) {
    int t = wgid + it * 4096;
    const float4* xr = (const float4*)(x + (size_t)t * H_DIM);
    us4* xbr = (us4*)(xb + (size_t)t * H_DIM);
    float l[E_NUM];
#pragma unroll
    for (int e = 0; e < E_NUM; e++) l[e] = 0.f;
#pragma unroll
    for (int i = 0; i < 4; i++) {
      int j = i * 64 + lane;
      float4 v = xr[j];
      us4 pk;
      pk[0] = f2bf(v.x); pk[1] = f2bf(v.y); pk[2] = f2bf(v.z); pk[3] = f2bf(v.w);
      xbr[j] = pk;
      int h = j * 4;
#pragma unroll
      for (int e = 0; e < E_NUM; e++) {
        const f32x4 wv = *(const f32x4*)&wg[e][h];
        l[e] = fmaf(v.x, wv[0], l[e]);
        l[e] = fmaf(v.y, wv[1], l[e]);
        l[e] = fmaf(v.z, wv[2], l[e]);
        l[e] = fmaf(v.w, wv[3], l[e]);
      }
    }
#pragma unroll
    for (int off = 32; off > 0; off >>= 1) {
#pragma unroll
      for (int e = 0; e < E_NUM; e++) l[e] += __shfl_xor(l[e], off, 64);
    }
    if (lane == 0) {
      float mx = l[0];
#pragma unroll
      for (int e = 1; e < E_NUM; e++) mx = fmaxf(mx, l[e]);
      float p[E_NUM]; float se = 0.f;
#pragma unroll
      for (int e = 0; e < E_NUM; e++) { p[e] = expf(l[e] - mx); se += p[e]; }
      float logz = logf(se) + mx;
      int e0 = 0; float b0 = p[0];
#pragma unroll
      for (int e = 1; e < E_NUM; e++) if (p[e] > b0) { b0 = p[e]; e0 = e; }
      int e1 = -1; float b1 = -1.f;
#pragma unroll
      for (int e = 0; e < E_NUM; e++) if (e != e0 && p[e] > b1) { b1 = p[e]; e1 = e; }
      float w0 = b0 / se, w1 = b1 / se;
      TopK tk; tk.e0 = e0; tk.e1 = e1; tk.w0 = w0; tk.w1 = w1;
      topk[t] = tk;
      atomicAdd(&cnt[e0], 1);
      atomicAdd(&cnt[8 + e1], 1);
      zacc += logz * logz;
      c0 += (e0 == 0 || e1 == 0) ? 1.f : 0.f;
      c1 += (e0 == 1 || e1 == 1) ? 1.f : 0.f;
      s0 += w0; s1 += w1;
    }
  }
  if (lane == 0) {
    sred[wid][0] = zacc; sred[wid][1] = c0; sred[wid][2] = c1;
    sred[wid][3] = s0;   sred[wid][4] = s1;
  }
  __syncthreads();
  if (tid == 0) {
    float a[5] = {0.f, 0.f, 0.f, 0.f, 0.f};
    for (int w2 = 0; w2 < 4; w2++)
      for (int k = 0; k < 5; k++) a[k] += sred[w2][k];
    for (int k = 0; k < 5; k++) atomicAdd(&scal[k], a[k]);
  }
  if (tid < 16 && cnt[tid]) atomicAdd(&counts[tid], cnt[tid]);
}

// ---------------- offsets padded to 256 rows per (rank, expert)
__global__ void scan_kernel(const int* __restrict__ counts, int* __restrict__ po,
                            int* __restrict__ tile_expert) {
  if (threadIdx.x == 0) {
    for (int r = 0; r < 2; r++) {
      int off = 0, ti = 0;
      for (int e = 0; e < E_NUM; e++) {
        po[r * 8 + e] = r * TPR * 256 + off;
        int nt = (counts[r * 8 + e] + 255) >> 8;
        for (int j = 0; j < nt; j++) tile_expert[r * TPR + ti++] = e;
        off += nt << 8;
      }
      while (ti < TPR) tile_expert[r * TPR + ti++] = -1;
    }
  }
}

__global__ __launch_bounds__(256) void assign_kernel(
    const TopK* __restrict__ topk, const int* __restrict__ po,
    int* __restrict__ cursors, int* __restrict__ pair_token,
    float* __restrict__ pair_w) {
  int t = blockIdx.x * 256 + threadIdx.x;
  if (t >= T_TOKENS) return;
  TopK tk = topk[t];
  int p0 = po[tk.e0] + atomicAdd(&cursors[tk.e0], 1);
  pair_token[p0] = t; pair_w[p0] = tk.w0;
  int p1 = po[8 + tk.e1] + atomicAdd(&cursors[8 + tk.e1], 1);
  pair_token[p1] = t; pair_w[p1] = tk.w1;
}

// ---------------- grouped GEMM, 256x256 tile, 8 waves, BK=64, 4-phase counted-vmcnt
// LDS 128KB dynamic: 2 bufs x { A_k0 16K | A_k1 16K | B_k0 16K | B_k1 16K }
// MODE 0: hmid[p,:] = gelu(xb[tok(p),:] @ W1t[e]^T)           (K=1024, N=2048)
// MODE 1: out[tok(p),:] = w(p) * (hmid[p,:] @ W2t[e]^T) store (K=2048, N=1024)
// MODE 2: out[tok(p),:] += w(p) * (hmid[p,:] @ W2t[e]^T) RMW  (K=2048, N=1024)
template <int MODE, int K, int N, int NTILES>
__global__ __launch_bounds__(512, 1) void moe_gemm8(
    const unsigned short* __restrict__ A, const unsigned short* __restrict__ Bt,
    const int* __restrict__ pair_token, const float* __restrict__ pair_w,
    const int* __restrict__ tile_expert, int tile_base,
    unsigned short* __restrict__ hmid, float* __restrict__ outp) {
  constexpr int NBN = N / 256;
  constexpr int NBLK = NBN * NTILES;           // % 8 == 0 by construction
  constexpr int NTk = K / 64;
  int l = blockIdx.x;
  int c = (l & 7) * (NBLK / 8) + (l >> 3);     // bijective XCD-chunked remap
  int mt = tile_base + (c % NTILES);           // m fast-varying: XCD shares B n-panel
  int nb = c / NTILES;
  int e = tile_expert[mt];
  if (e < 0) return;
  int m0 = mt << 8, n0 = nb << 8;

  extern __shared__ __align__(16) char smem_raw[];
  unsigned short* lds = (unsigned short*)smem_raw;   // 65536 elems = 128KB

  int tid = threadIdx.x, lane = tid & 63, wid = tid >> 6;
  int wm = wid >> 2, wn = wid & 3;             // 2 x 4 wave grid, wave tile 128x64
  int lo = lane & 15, hi = lane >> 4;
  int sw = (lo >> 1) & 3;
  int xk = (hi ^ sw) * 8;                      // swizzled chunk (elems within 32-elem half-row)

  // read bases (element offsets within a buffer)
  int aRB = (wm * 128 + lo) * 32 + xk;         // + mh*2048 + mf*512 ; +8192 for ks1
  int bRB = 16384 + (wn * 64 + lo) * 32 + xk;  // + nf*512 ; +8192 for ks1

  // ---- stage side: thread (wid, j=0/1) owns rows r0, r1; source chunk pre-swizzled
  int r0 = wid * 32 + (lane >> 2);
  int r1 = r0 + 16;
  int csrc = (lane & 3) ^ ((lane >> 3) & 3);   // == (lane&3) ^ ((r>>1)&3), same for r0/r1
  const unsigned short *aB0, *aB1, *bB0, *bB1;
  if (MODE == 0) {
    int t0 = pair_token[m0 + r0]; if (t0 < 0) t0 = 0;
    int t1 = pair_token[m0 + r1]; if (t1 < 0) t1 = 0;
    aB0 = A + (size_t)t0 * K + csrc * 8;
    aB1 = A + (size_t)t1 * K + csrc * 8;
  } else {
    aB0 = A + (size_t)(m0 + r0) * K + csrc * 8;
    aB1 = A + (size_t)(m0 + r1) * K + csrc * 8;
  }
  bB0 = Bt + ((size_t)e * N + n0 + r0) * K + csrc * 8;
  bB1 = Bt + ((size_t)e * N + n0 + r1) * K + csrc * 8;
  int dA = wid * 1024;                         // dest elem base (+ lane*8 implicit)

#define SA0(s, bo) do { int ko = (s) * 64; \
    gload_lds16(aB0 + ko, lds + (bo) + dA); \
    gload_lds16(aB1 + ko, lds + (bo) + dA + 512); } while (0)
#define SA1(s, bo) do { int ko = (s) * 64 + 32; \
    gload_lds16(aB0 + ko, lds + (bo) + 8192 + dA); \
    gload_lds16(aB1 + ko, lds + (bo) + 8192 + dA + 512); } while (0)
#define SB0(s, bo) do { int ko = (s) * 64; \
    gload_lds16(bB0 + ko, lds + (bo) + 16384 + dA); \
    gload_lds16(bB1 + ko, lds + (bo) + 16384 + dA + 512); } while (0)
#define SB1(s, bo) do { int ko = (s) * 64 + 32; \
    gload_lds16(bB0 + ko, lds + (bo) + 24576 + dA); \
    gload_lds16(bB1 + ko, lds + (bo) + 24576 + dA + 512); } while (0)
#define BAR() do { asm volatile("s_barrier" ::: "memory"); \
    __builtin_amdgcn_sched_barrier(0); } while (0)
#define VMC(n) do { asm volatile("s_waitcnt vmcnt(" #n ")" ::: "memory"); \
    __builtin_amdgcn_sched_barrier(0); } while (0)
#define LDA(mh, ks, bo) do { _Pragma("unroll") \
    for (int mf = 0; mf < 4; mf++) \
      afr[mf] = *(const bf16x8*)&lds[(bo) + (ks) * 8192 + aRB + (mh) * 2048 + mf * 512]; } while (0)
#define LDB(dst, ks, bo) do { _Pragma("unroll") \
    for (int nf = 0; nf < 4; nf++) \
      dst[nf] = *(const bf16x8*)&lds[(bo) + (ks) * 8192 + bRB + nf * 512]; } while (0)
#define MM(am0, bq) do { __builtin_amdgcn_s_setprio(1); \
    _Pragma("unroll") for (int mf = 0; mf < 4; mf++) \
    _Pragma("unroll") for (int nf = 0; nf < 4; nf++) \
      acc[(am0) + mf][nf] = __builtin_amdgcn_mfma_f32_16x16x32_bf16( \
          bq[nf], afr[mf], acc[(am0) + mf][nf], 0, 0, 0); \
    __builtin_amdgcn_s_setprio(0); } while (0)

  f32x4 acc[8][4];
#pragma unroll
  for (int i = 0; i < 8; i++)
#pragma unroll
    for (int j = 0; j < 4; j++) acc[i][j] = (f32x4){0.f, 0.f, 0.f, 0.f};

  // prologue: tile0 complete (6+2 loads) + tile1's B halves and A_k0, steady-state order
  SA0(0, 0); SB0(0, 0); SB1(0, 0);
  SA1(0, 0); SB0(1, 32768); SB1(1, 32768); SA0(1, 32768);
  VMC(8); BAR();

  bf16x8 afr[4], bfr0[4], bfr1[4];
  for (int t = 0; t < NTk; ++t) {
    int bo = (t & 1) << 15;
    int bw = bo ^ 32768;
    int s1 = min(t + 1, NTk - 1), s2 = min(t + 2, NTk - 1);
    // P0: (mh0, ks0) + B ks0; issue A_k1(t+1) -> other buf
    LDA(0, 0, bo); LDB(bfr0, 0, bo);
    SA1(s1, bw);
    BAR();
    MM(0, bfr0);
    VMC(6); BAR();
    // P1: (mh0, ks1) + B ks1; issue B_k0(t+2) -> current buf (region dead after P0)
    LDA(0, 1, bo); LDB(bfr1, 1, bo);
    SB0(s2, bo);
    BAR();
    MM(0, bfr1);
    BAR();
    // P2: (mh1, ks0); issue B_k1(t+2) (dead after P1)
    LDA(1, 0, bo);
    SB1(s2, bo);
    BAR();
    MM(4, bfr0);
    BAR();
    // P3: (mh1, ks1); issue A_k0(t+2) (dead after P2)
    LDA(1, 1, bo);
    SA0(s2, bo);
    BAR();
    MM(4, bfr1);
    VMC(8); BAR();
  }
  // drain all outstanding global_load_lds before epilogue / endpgm
  asm volatile("s_waitcnt vmcnt(0)" ::: "memory");
  __builtin_amdgcn_sched_barrier(0);
#undef SA0
#undef SA1
#undef SB0
#undef SB1
#undef BAR
#undef VMC
#undef LDA
#undef LDB
#undef MM

  if (MODE == 0) {
#pragma unroll
    for (int mh = 0; mh < 2; mh++)
#pragma unroll
      for (int mf = 0; mf < 4; mf++) {
        size_t p = m0 + wm * 128 + mh * 64 + mf * 16 + lo;
#pragma unroll
        for (int nf = 0; nf < 4; nf++) {
          int f = n0 + wn * 64 + nf * 16 + hi * 4;
          us4 pk;
#pragma unroll
          for (int r = 0; r < 4; r++) {
            float v = acc[mh * 4 + mf][nf][r];
            float u = fmaf(0.044715f * v * v, v, v);
            float s = 1.f / (1.f + __expf(-1.5957691216057308f * u));
            pk[r] = f2bf(v * s);
          }
          *(us4*)&hmid[p * (size_t)N + f] = pk;
        }
      }
  } else {
#pragma unroll
    for (int mh = 0; mh < 2; mh++)
#pragma unroll
      for (int mf = 0; mf < 4; mf++) {
        int p = m0 + wm * 128 + mh * 64 + mf * 16 + lo;
        int t = pair_token[p];
        if (t < 0) continue;
        float w = pair_w[p];
        float* orow = outp + (size_t)t * N;
#pragma unroll
        for (int nf = 0; nf < 4; nf++) {
          int f = n0 + wn * 64 + nf * 16 + hi * 4;
          f32x4 v;
#pragma unroll
          for (int r = 0; r < 4; r++) v[r] = w * acc[mh * 4 + mf][nf][r];
          if (MODE == 2) v += *(const f32x4*)&orow[f];  // non-atomic RMW: t unique per dispatch
          *(f32x4*)&orow[f] = v;
        }
      }
  }
}

__global__ void finalize_kernel(const float* __restrict__ scal,
                                float* __restrict__ outTail) {
  if (threadIdx.x == 0 && blockIdx.x == 0) {
    float invT = 1.f / (float)T_TOKENS;
    outTail[0] = scal[0] * invT;  // z_loss
    float tpe0 = scal[1] * invT, tpe1 = scal[2] * invT;
    float rp0 = scal[3] * invT, rp1 = scal[4] * invT;
    outTail[1] = (tpe0 * rp0 + tpe1 * rp1) * 0.5f * 4.f;  // aux (K=2 one_hot path)
  }
}

extern "C" void kernel_launch(void* const* d_in, const int* in_sizes, int n_in,
                              void* d_out, int out_size, void* d_ws, size_t ws_size,
                              hipStream_t stream) {
  const float* x  = (const float*)d_in[0];
  const float* Wg = (const float*)d_in[1];
  const float* W1 = (const float*)d_in[2];
  const float* W2 = (const float*)d_in[3];
  float* outp = (float*)d_out;

  char* w = (char*)d_ws;
  auto alloc = [&](size_t b) { char* p = w; w += (b + 511) & ~(size_t)511; return p; };
  float* scal        = (float*)alloc(32);
  int*   counts      = (int*)alloc(64);
  int*   cursors     = (int*)alloc(64);
  int*   po          = (int*)alloc(64);
  int*   tile_expert = (int*)alloc(TOT_T * 4);
  TopK*  topk        = (TopK*)alloc((size_t)T_TOKENS * sizeof(TopK));
  int*   pair_token  = (int*)alloc((size_t)MAX_PAIRS * 4);
  float* pair_w      = (float*)alloc((size_t)MAX_PAIRS * 4);
  // staged buffers padded +512B (staging tail prefetch may touch up to +64B past end)
  unsigned short* xb   = (unsigned short*)alloc((size_t)T_TOKENS * H_DIM * 2 + 512);
  unsigned short* w1t  = (unsigned short*)alloc((size_t)E_NUM * F_DIM * H_DIM * 2 + 512);
  unsigned short* hmid = (unsigned short*)alloc((size_t)MAX_PAIRS * F_DIM * 2 + 512);
  // w2t ALIASES xb (xb dead after GEMM1; W2 transpose launched after GEMM1)
  unsigned short* w2t  = xb;

  // allow 128KB dynamic LDS for the GEMM kernels (idempotent host call, capture-safe)
  hipFuncSetAttribute((const void*)&moe_gemm8<0, H_DIM, F_DIM, TOT_T>,
                      hipFuncAttributeMaxDynamicSharedMemorySize, 131072);
  hipFuncSetAttribute((const void*)&moe_gemm8<1, F_DIM, H_DIM, TPR>,
                      hipFuncAttributeMaxDynamicSharedMemorySize, 131072);
  hipFuncSetAttribute((const void*)&moe_gemm8<2, F_DIM, H_DIM, TPR>,
                      hipFuncAttributeMaxDynamicSharedMemorySize, 131072);

  hipMemsetAsync(scal, 0, 32, stream);
  hipMemsetAsync(counts, 0, 64, stream);
  hipMemsetAsync(cursors, 0, 64, stream);
  hipMemsetAsync(pair_token, 0xFF, (size_t)MAX_PAIRS * 4, stream);  // -1

  dim3 b256(256), b512(512);
  // W1 [E][H][F] -> w1t [E][F][H]
  transpose_cast<<<dim3(F_DIM / 64, H_DIM / 64, E_NUM), b256, 0, stream>>>(W1, w1t, H_DIM, F_DIM);
  router_kernel<<<1024, b256, 0, stream>>>(x, Wg, xb, topk, counts, scal);
  scan_kernel<<<1, 64, 0, stream>>>(counts, po, tile_expert);
  assign_kernel<<<T_TOKENS / 256, b256, 0, stream>>>(topk, po, cursors, pair_token, pair_w);
  // GEMM1: hmid = gelu(gather(xb) @ W1t^T), both rank regions, one dispatch
  moe_gemm8<0, H_DIM, F_DIM, TOT_T><<<dim3((F_DIM / 256) * TOT_T), b512, 131072, stream>>>(
      xb, w1t, pair_token, pair_w, tile_expert, 0, hmid, nullptr);
  // W2 [E][F][H] -> w2t [E][H][F]  (into xb's space — xb dead now)
  transpose_cast<<<dim3(H_DIM / 64, F_DIM / 64, E_NUM), b256, 0, stream>>>(W2, w2t, F_DIM, H_DIM);
  // GEMM2 rank-0: plain store (every token exactly once)
  moe_gemm8<1, F_DIM, H_DIM, TPR><<<dim3((H_DIM / 256) * TPR), b512, 131072, stream>>>(
      hmid, w2t, pair_token, pair_w, tile_expert, 0, nullptr, outp);
  // GEMM2 rank-1: non-atomic RMW add (every token exactly once)
  moe_gemm8<2, F_DIM, H_DIM, TPR><<<dim3((H_DIM / 256) * TPR), b512, 131072, stream>>>(
      hmid, w2t, pair_token, pair_w, tile_expert, TPR, nullptr, outp);
  finalize_kernel<<<1, 64, 0, stream>>>(scal, outp + (size_t)T_TOKENS * H_DIM);
}